// Round 2
// baseline (132.051 us; speedup 1.0000x reference)
//
#include <hip/hip_runtime.h>

// SplineDisp: field[v] = ma @ (g(v) + cubic_bspline_pull(coeff, g(v))) where
// g(v) = fa @ v, fa = inv(affine)@fix_affine, ma = inv(mov_affine)@affine.
// Fixed size: coeff [80,80,80,3] f32, out [160,160,160,3] f32.
// R2: coeff repacked to [80,80,80,4] float4 in d_ws -> 1 dwordx4 per tap
//     (64 loads/thread instead of 192 scalar), wrap via one % + cond-sub.

#define CX 80
#define CC 3
#define FD 160
// byte strides in the repacked 4-channel volume
#define BSX (CX * CX * 16)   // 102400
#define BSY (CX * 16)        // 1280
#define BSZ 16

__device__ inline void inv4(const float* m, float* inv) {
    inv[0]  =  m[5]*m[10]*m[15] - m[5]*m[11]*m[14] - m[9]*m[6]*m[15] + m[9]*m[7]*m[14] + m[13]*m[6]*m[11] - m[13]*m[7]*m[10];
    inv[4]  = -m[4]*m[10]*m[15] + m[4]*m[11]*m[14] + m[8]*m[6]*m[15] - m[8]*m[7]*m[14] - m[12]*m[6]*m[11] + m[12]*m[7]*m[10];
    inv[8]  =  m[4]*m[9]*m[15]  - m[4]*m[11]*m[13] - m[8]*m[5]*m[15] + m[8]*m[7]*m[13] + m[12]*m[5]*m[11] - m[12]*m[7]*m[9];
    inv[12] = -m[4]*m[9]*m[14]  + m[4]*m[10]*m[13] + m[8]*m[5]*m[14] - m[8]*m[6]*m[13] - m[12]*m[5]*m[10] + m[12]*m[6]*m[9];
    inv[1]  = -m[1]*m[10]*m[15] + m[1]*m[11]*m[14] + m[9]*m[2]*m[15] - m[9]*m[3]*m[14] - m[13]*m[2]*m[11] + m[13]*m[3]*m[10];
    inv[5]  =  m[0]*m[10]*m[15] - m[0]*m[11]*m[14] - m[8]*m[2]*m[15] + m[8]*m[3]*m[14] + m[12]*m[2]*m[11] - m[12]*m[3]*m[10];
    inv[9]  = -m[0]*m[9]*m[15]  + m[0]*m[11]*m[13] + m[8]*m[1]*m[15] - m[8]*m[3]*m[13] - m[12]*m[1]*m[11] + m[12]*m[3]*m[9];
    inv[13] =  m[0]*m[9]*m[14]  - m[0]*m[10]*m[13] - m[8]*m[1]*m[14] + m[8]*m[2]*m[13] + m[12]*m[1]*m[10] - m[12]*m[2]*m[9];
    inv[2]  =  m[1]*m[6]*m[15]  - m[1]*m[7]*m[14]  - m[5]*m[2]*m[15] + m[5]*m[3]*m[14] + m[13]*m[2]*m[7]  - m[13]*m[3]*m[6];
    inv[6]  = -m[0]*m[6]*m[15]  + m[0]*m[7]*m[14]  + m[4]*m[2]*m[15] - m[4]*m[3]*m[14] - m[12]*m[2]*m[7]  + m[12]*m[3]*m[6];
    inv[10] =  m[0]*m[5]*m[15]  - m[0]*m[7]*m[13]  - m[4]*m[1]*m[15] + m[4]*m[3]*m[13] + m[12]*m[1]*m[7]  - m[12]*m[3]*m[5];
    inv[14] = -m[0]*m[5]*m[14]  + m[0]*m[6]*m[13]  + m[4]*m[1]*m[14] - m[4]*m[2]*m[13] - m[12]*m[1]*m[6]  + m[12]*m[2]*m[5];
    inv[3]  = -m[1]*m[6]*m[11]  + m[1]*m[7]*m[10]  + m[5]*m[2]*m[11] - m[5]*m[3]*m[10] - m[9]*m[2]*m[7]   + m[9]*m[3]*m[6];
    inv[7]  =  m[0]*m[6]*m[11]  - m[0]*m[7]*m[10]  - m[4]*m[2]*m[11] + m[4]*m[3]*m[10] + m[8]*m[2]*m[7]   - m[8]*m[3]*m[6];
    inv[11] = -m[0]*m[5]*m[11]  + m[0]*m[7]*m[9]   + m[4]*m[1]*m[11] - m[4]*m[3]*m[9]  - m[8]*m[1]*m[7]   + m[8]*m[3]*m[5];
    inv[15] =  m[0]*m[5]*m[10]  - m[0]*m[6]*m[9]   - m[4]*m[1]*m[10] + m[4]*m[2]*m[9]  + m[8]*m[1]*m[6]   - m[8]*m[2]*m[5];
    float det = m[0]*inv[0] + m[1]*inv[4] + m[2]*inv[8] + m[3]*inv[12];
    float rdet = 1.0f / det;
    for (int i = 0; i < 16; ++i) inv[i] *= rdet;
}

__global__ void setup_mats(const float* __restrict__ affine,
                           const float* __restrict__ fix_aff,
                           const float* __restrict__ mov_aff,
                           float* __restrict__ M) {
    if (threadIdx.x != 0 || blockIdx.x != 0) return;
    float invA[16], invM[16];
    inv4(affine, invA);
    inv4(mov_aff, invM);
    for (int r = 0; r < 4; ++r)
        for (int c = 0; c < 4; ++c) {
            float s = 0.f;
            for (int k = 0; k < 4; ++k) s += invA[r*4+k] * fix_aff[k*4+c];
            M[r*4+c] = s;
        }
    for (int r = 0; r < 4; ++r)
        for (int c = 0; c < 4; ++c) {
            float s = 0.f;
            for (int k = 0; k < 4; ++k) s += invM[r*4+k] * affine[k*4+c];
            M[16 + r*4+c] = s;
        }
}

// Repack [80,80,80,3] -> [80,80,80,4] (w lane zero). 512000 voxels.
__global__ __launch_bounds__(256) void repack_c4(const float* __restrict__ c3,
                                                 float4* __restrict__ c4) {
    int t = blockIdx.x * 256 + threadIdx.x;   // 2000 * 256 = 512000 exactly
    const float* p = c3 + t * 3;
    float4 v;
    v.x = p[0]; v.y = p[1]; v.z = p[2]; v.w = 0.f;
    c4[t] = v;
}

__device__ inline void bspline_w(float t, float w[4]) {
    float t2 = t * t;
    float t3 = t2 * t;
    const float s = 1.0f / 6.0f;
    w[0] = (1.f - 3.f*t + 3.f*t2 - t3) * s;
    w[1] = (4.f - 6.f*t2 + 3.f*t3) * s;
    w[2] = (1.f + 3.f*t + 3.f*t2 - 3.f*t3) * s;
    w[3] = t3 * s;
}

__device__ inline int wrap80(int v) {
    int r = v % CX;
    return (r < 0) ? r + CX : r;
}

__global__ __launch_bounds__(256) void spline_field4(const char* __restrict__ coeff4,
                                                     const float* __restrict__ M,
                                                     float* __restrict__ out) {
    int tid = blockIdx.x * 256 + threadIdx.x;
    int k = tid % FD;
    int t2 = tid / FD;
    int j = t2 % FD;
    int i = t2 / FD;

    float fi = (float)i, fj = (float)j, fk = (float)k;
    float gx = M[0]*fi + M[1]*fj + M[2]*fk  + M[3];
    float gy = M[4]*fi + M[5]*fj + M[6]*fk  + M[7];
    float gz = M[8]*fi + M[9]*fj + M[10]*fk + M[11];

    float fx = floorf(gx), fy = floorf(gy), fz = floorf(gz);
    float tx = gx - fx, ty = gy - fy, tz = gz - fz;

    float wx[4], wy[4], wz[4];
    bspline_w(tx, wx);
    bspline_w(ty, wy);
    bspline_w(tz, wz);

    // wrap base once per axis; taps then need only one conditional subtract
    int bxw = wrap80((int)fx - 1);
    int byw = wrap80((int)fy - 1);
    int bzw = wrap80((int)fz - 1);

    int ox[4], oy[4], oz[4];
#pragma unroll
    for (int a = 0; a < 4; ++a) {
        int xa = bxw + a; if (xa >= CX) xa -= CX;
        int ya = byw + a; if (ya >= CX) ya -= CX;
        int za = bzw + a; if (za >= CX) za -= CX;
        ox[a] = xa * BSX;
        oy[a] = ya * BSY;
        oz[a] = za * BSZ;
    }

    float a0 = 0.f, a1 = 0.f, a2 = 0.f;
#pragma unroll
    for (int a = 0; a < 4; ++a) {
        float wa = wx[a];
        int oa = ox[a];
#pragma unroll
        for (int b = 0; b < 4; ++b) {
            float wab = wa * wy[b];
            int oab = oa + oy[b];
#pragma unroll
            for (int c = 0; c < 4; ++c) {
                float w = wab * wz[c];
                float4 v = *(const float4*)(coeff4 + (oab + oz[c]));
                a0 = fmaf(w, v.x, a0);
                a1 = fmaf(w, v.y, a1);
                a2 = fmaf(w, v.z, a2);
            }
        }
    }

    float ux = gx + a0, uy = gy + a1, uz = gz + a2;
    float o0 = M[16]*ux + M[17]*uy + M[18]*uz + M[19];
    float o1 = M[20]*ux + M[21]*uy + M[22]*uz + M[23];
    float o2 = M[24]*ux + M[25]*uy + M[26]*uz + M[27];

    out[tid*3 + 0] = o0;
    out[tid*3 + 1] = o1;
    out[tid*3 + 2] = o2;
}

// ---- fallback (R1 path) if ws too small for the repacked volume ----
__global__ __launch_bounds__(256) void spline_field3(const float* __restrict__ coeff,
                                                     const float* __restrict__ M,
                                                     float* __restrict__ out) {
    int tid = blockIdx.x * 256 + threadIdx.x;
    int k = tid % FD;
    int t2 = tid / FD;
    int j = t2 % FD;
    int i = t2 / FD;

    float fi = (float)i, fj = (float)j, fk = (float)k;
    float gx = M[0]*fi + M[1]*fj + M[2]*fk  + M[3];
    float gy = M[4]*fi + M[5]*fj + M[6]*fk  + M[7];
    float gz = M[8]*fi + M[9]*fj + M[10]*fk + M[11];

    float fx = floorf(gx), fy = floorf(gy), fz = floorf(gz);
    float tx = gx - fx, ty = gy - fy, tz = gz - fz;

    float wx[4], wy[4], wz[4];
    bspline_w(tx, wx);
    bspline_w(ty, wy);
    bspline_w(tz, wz);

    int bxw = wrap80((int)fx - 1);
    int byw = wrap80((int)fy - 1);
    int bzw = wrap80((int)fz - 1);

    int ox[4], oy[4], oz[4];
#pragma unroll
    for (int a = 0; a < 4; ++a) {
        int xa = bxw + a; if (xa >= CX) xa -= CX;
        int ya = byw + a; if (ya >= CX) ya -= CX;
        int za = bzw + a; if (za >= CX) za -= CX;
        ox[a] = xa * (CX*CX*CC);
        oy[a] = ya * (CX*CC);
        oz[a] = za * CC;
    }

    float a0 = 0.f, a1 = 0.f, a2 = 0.f;
#pragma unroll
    for (int a = 0; a < 4; ++a) {
        float wa = wx[a];
        int oa = ox[a];
#pragma unroll
        for (int b = 0; b < 4; ++b) {
            float wab = wa * wy[b];
            int oab = oa + oy[b];
#pragma unroll
            for (int c = 0; c < 4; ++c) {
                float w = wab * wz[c];
                const float* p = coeff + (oab + oz[c]);
                a0 = fmaf(w, p[0], a0);
                a1 = fmaf(w, p[1], a1);
                a2 = fmaf(w, p[2], a2);
            }
        }
    }

    float ux = gx + a0, uy = gy + a1, uz = gz + a2;
    float o0 = M[16]*ux + M[17]*uy + M[18]*uz + M[19];
    float o1 = M[20]*ux + M[21]*uy + M[22]*uz + M[23];
    float o2 = M[24]*ux + M[25]*uy + M[26]*uz + M[27];

    out[tid*3 + 0] = o0;
    out[tid*3 + 1] = o1;
    out[tid*3 + 2] = o2;
}

extern "C" void kernel_launch(void* const* d_in, const int* in_sizes, int n_in,
                              void* d_out, int out_size, void* d_ws, size_t ws_size,
                              hipStream_t stream) {
    const float* coeff    = (const float*)d_in[0];
    const float* affine   = (const float*)d_in[1];
    const float* fix_aff  = (const float*)d_in[2];
    const float* mov_aff  = (const float*)d_in[3];
    float* M = (float*)d_ws;                       // 32 floats at ws[0]
    char*  c4 = (char*)d_ws + 256;                 // repacked coeff, 8.192 MB
    float* out = (float*)d_out;

    const size_t need = 256 + (size_t)CX*CX*CX*16;

    setup_mats<<<1, 64, 0, stream>>>(affine, fix_aff, mov_aff, M);

    const int total = FD * FD * FD;                // 4,096,000
    const int blocks = total / 256;                // 16000

    if (ws_size >= need) {
        repack_c4<<<(CX*CX*CX)/256, 256, 0, stream>>>(coeff, (float4*)c4);
        spline_field4<<<blocks, 256, 0, stream>>>(c4, M, out);
    } else {
        spline_field3<<<blocks, 256, 0, stream>>>(coeff, M, out);
    }
}

// Round 3
// 54.554 us; speedup vs baseline: 2.4205x; 2.4205x over previous
//
#include <hip/hip_runtime.h>

// SplineDisp: field[v] = ma @ (g(v) + cubic_bspline_pull(coeff, g(v))),
// g(v) = fa @ v, fa = inv(affine)@fix_affine, ma = inv(mov_affine)@affine.
// Fixed size: coeff [80,80,80,3] f32, out [160,160,160,3] f32.
// R3: separable 3-pass (z, y, x) tensor-product interpolation when fa is
// axis-aligned (detected on device): 12 taps/voxel instead of 64, passes 2/3
// fully coalesced. Intermediates in d_ws. Uniform-branch fallback to direct
// 64-tap kernel when fa is not axis-aligned or ws too small.

#define CX 80
#define FD 160

__device__ inline void inv4(const float* m, float* inv) {
    inv[0]  =  m[5]*m[10]*m[15] - m[5]*m[11]*m[14] - m[9]*m[6]*m[15] + m[9]*m[7]*m[14] + m[13]*m[6]*m[11] - m[13]*m[7]*m[10];
    inv[4]  = -m[4]*m[10]*m[15] + m[4]*m[11]*m[14] + m[8]*m[6]*m[15] - m[8]*m[7]*m[14] - m[12]*m[6]*m[11] + m[12]*m[7]*m[10];
    inv[8]  =  m[4]*m[9]*m[15]  - m[4]*m[11]*m[13] - m[8]*m[5]*m[15] + m[8]*m[7]*m[13] + m[12]*m[5]*m[11] - m[12]*m[7]*m[9];
    inv[12] = -m[4]*m[9]*m[14]  + m[4]*m[10]*m[13] + m[8]*m[5]*m[14] - m[8]*m[6]*m[13] - m[12]*m[5]*m[10] + m[12]*m[6]*m[9];
    inv[1]  = -m[1]*m[10]*m[15] + m[1]*m[11]*m[14] + m[9]*m[2]*m[15] - m[9]*m[3]*m[14] - m[13]*m[2]*m[11] + m[13]*m[3]*m[10];
    inv[5]  =  m[0]*m[10]*m[15] - m[0]*m[11]*m[14] - m[8]*m[2]*m[15] + m[8]*m[3]*m[14] + m[12]*m[2]*m[11] - m[12]*m[3]*m[10];
    inv[9]  = -m[0]*m[9]*m[15]  + m[0]*m[11]*m[13] + m[8]*m[1]*m[15] - m[8]*m[3]*m[13] - m[12]*m[1]*m[11] + m[12]*m[3]*m[9];
    inv[13] =  m[0]*m[9]*m[14]  - m[0]*m[10]*m[13] - m[8]*m[1]*m[14] + m[8]*m[2]*m[13] + m[12]*m[1]*m[10] - m[12]*m[2]*m[9];
    inv[2]  =  m[1]*m[6]*m[15]  - m[1]*m[7]*m[14]  - m[5]*m[2]*m[15] + m[5]*m[3]*m[14] + m[13]*m[2]*m[7]  - m[13]*m[3]*m[6];
    inv[6]  = -m[0]*m[6]*m[15]  + m[0]*m[7]*m[14]  + m[4]*m[2]*m[15] - m[4]*m[3]*m[14] - m[12]*m[2]*m[7]  + m[12]*m[3]*m[6];
    inv[10] =  m[0]*m[5]*m[15]  - m[0]*m[7]*m[13]  - m[4]*m[1]*m[15] + m[4]*m[3]*m[13] + m[12]*m[1]*m[7]  - m[12]*m[3]*m[5];
    inv[14] = -m[0]*m[5]*m[14]  + m[0]*m[6]*m[13]  + m[4]*m[1]*m[14] - m[4]*m[2]*m[13] - m[12]*m[1]*m[6]  + m[12]*m[2]*m[5];
    inv[3]  = -m[1]*m[6]*m[11]  + m[1]*m[7]*m[10]  + m[5]*m[2]*m[11] - m[5]*m[3]*m[10] - m[9]*m[2]*m[7]   + m[9]*m[3]*m[6];
    inv[7]  =  m[0]*m[6]*m[11]  - m[0]*m[7]*m[10]  - m[4]*m[2]*m[11] + m[4]*m[3]*m[10] + m[8]*m[2]*m[7]   - m[8]*m[3]*m[6];
    inv[11] = -m[0]*m[5]*m[11]  + m[0]*m[7]*m[9]   + m[4]*m[1]*m[11] - m[4]*m[3]*m[9]  - m[8]*m[1]*m[7]   + m[8]*m[3]*m[5];
    inv[15] =  m[0]*m[5]*m[10]  - m[0]*m[6]*m[9]   - m[4]*m[1]*m[10] + m[4]*m[2]*m[9]  + m[8]*m[1]*m[6]   - m[8]*m[2]*m[5];
    float det = m[0]*inv[0] + m[1]*inv[4] + m[2]*inv[8] + m[3]*inv[12];
    float rdet = 1.0f / det;
    for (int i = 0; i < 16; ++i) inv[i] *= rdet;
}

// M[0..15]=fa, M[16..31]=ma, M[32]=separable flag
__global__ void setup_mats(const float* __restrict__ affine,
                           const float* __restrict__ fix_aff,
                           const float* __restrict__ mov_aff,
                           float* __restrict__ M) {
    if (threadIdx.x != 0 || blockIdx.x != 0) return;
    float invA[16], invM[16];
    inv4(affine, invA);
    inv4(mov_aff, invM);
    for (int r = 0; r < 4; ++r)
        for (int c = 0; c < 4; ++c) {
            float s = 0.f;
            for (int k = 0; k < 4; ++k) s += invA[r*4+k] * fix_aff[k*4+c];
            M[r*4+c] = s;
        }
    for (int r = 0; r < 4; ++r)
        for (int c = 0; c < 4; ++c) {
            float s = 0.f;
            for (int k = 0; k < 4; ++k) s += invM[r*4+k] * affine[k*4+c];
            M[16 + r*4+c] = s;
        }
    float od = fabsf(M[1]) + fabsf(M[2]) + fabsf(M[4]) + fabsf(M[6]) + fabsf(M[8]) + fabsf(M[9]);
    M[32] = (od < 1e-20f) ? 1.f : 0.f;
}

__device__ inline void bspline_w(float t, float w[4]) {
    float t2 = t * t;
    float t3 = t2 * t;
    const float s = 1.0f / 6.0f;
    w[0] = (1.f - 3.f*t + 3.f*t2 - t3) * s;
    w[1] = (4.f - 6.f*t2 + 3.f*t3) * s;
    w[2] = (1.f + 3.f*t + 3.f*t2 - 3.f*t3) * s;
    w[3] = t3 * s;
}

__device__ inline int wrap80(int v) {
    int r = v % CX;
    return (r < 0) ? r + CX : r;
}

// Pass 1: z-interp. T1[x][y][k] = sum_c wz[k][c] * coeff[x][y][zc], float4.
// 80*80*160 = 1,024,000 threads.
__global__ __launch_bounds__(256) void pass_z(const float* __restrict__ coeff,
                                              const float* __restrict__ M,
                                              float4* __restrict__ T1) {
    if (M[32] == 0.f) return;
    int tid = blockIdx.x * 256 + threadIdx.x;
    int k = tid % FD;
    int r = tid / FD;          // r = x*80 + y
    float gz = M[10] * (float)k + M[11];
    float fz = floorf(gz);
    float wz[4];
    bspline_w(gz - fz, wz);
    int bz = wrap80((int)fz - 1);
    const float* base = coeff + r * (CX * 3);
    float a0 = 0.f, a1 = 0.f, a2 = 0.f;
#pragma unroll
    for (int c = 0; c < 4; ++c) {
        int zc = bz + c; if (zc >= CX) zc -= CX;
        const float* p = base + zc * 3;
        float w = wz[c];
        a0 = fmaf(w, p[0], a0);
        a1 = fmaf(w, p[1], a1);
        a2 = fmaf(w, p[2], a2);
    }
    float4 v; v.x = a0; v.y = a1; v.z = a2; v.w = 0.f;
    T1[tid] = v;
}

// Pass 2: y-interp. T2[x][j][k] = sum_b wy[j][b] * T1[x][yb][k].
// 80*160*160 = 2,048,000 threads; taps fully coalesced along k.
__global__ __launch_bounds__(256) void pass_y(const float* __restrict__ M,
                                              const float4* __restrict__ T1,
                                              float4* __restrict__ T2) {
    if (M[32] == 0.f) return;
    int tid = blockIdx.x * 256 + threadIdx.x;
    int k = tid % FD;
    int r = tid / FD;
    int j = r % FD;
    int x = r / FD;
    float gy = M[5] * (float)j + M[7];
    float fy = floorf(gy);
    float wy[4];
    bspline_w(gy - fy, wy);
    int by = wrap80((int)fy - 1);
    float a0 = 0.f, a1 = 0.f, a2 = 0.f;
#pragma unroll
    for (int b = 0; b < 4; ++b) {
        int yb = by + b; if (yb >= CX) yb -= CX;
        float4 v = T1[(x * CX + yb) * FD + k];
        float w = wy[b];
        a0 = fmaf(w, v.x, a0);
        a1 = fmaf(w, v.y, a1);
        a2 = fmaf(w, v.z, a2);
    }
    float4 v; v.x = a0; v.y = a1; v.z = a2; v.w = 0.f;
    T2[tid] = v;   // (x*FD + j)*FD + k == tid
}

// Pass 3: x-interp + displacement add + ma affine. 160^3 threads.
// Non-separable fallback: full direct 64-tap evaluation (uniform branch).
__global__ __launch_bounds__(256) void pass_x(const float* __restrict__ coeff,
                                              const float* __restrict__ M,
                                              const float4* __restrict__ T2,
                                              float* __restrict__ out) {
    int tid = blockIdx.x * 256 + threadIdx.x;
    int k = tid % FD;
    int r = tid / FD;
    int j = r % FD;
    int i = r / FD;

    float a0, a1, a2, gx, gy, gz;
    if (M[32] != 0.f) {
        gx = M[0]  * (float)i + M[3];
        gy = M[5]  * (float)j + M[7];
        gz = M[10] * (float)k + M[11];
        float fx = floorf(gx);
        float wx[4];
        bspline_w(gx - fx, wx);
        int bx = wrap80((int)fx - 1);
        a0 = 0.f; a1 = 0.f; a2 = 0.f;
#pragma unroll
        for (int a = 0; a < 4; ++a) {
            int xa = bx + a; if (xa >= CX) xa -= CX;
            float4 v = T2[(xa * FD + j) * FD + k];
            float w = wx[a];
            a0 = fmaf(w, v.x, a0);
            a1 = fmaf(w, v.y, a1);
            a2 = fmaf(w, v.z, a2);
        }
    } else {
        float fi = (float)i, fj = (float)j, fk = (float)k;
        gx = M[0]*fi + M[1]*fj + M[2]*fk  + M[3];
        gy = M[4]*fi + M[5]*fj + M[6]*fk  + M[7];
        gz = M[8]*fi + M[9]*fj + M[10]*fk + M[11];
        float fx = floorf(gx), fy = floorf(gy), fz = floorf(gz);
        float wx[4], wy[4], wz[4];
        bspline_w(gx - fx, wx);
        bspline_w(gy - fy, wy);
        bspline_w(gz - fz, wz);
        int bxw = wrap80((int)fx - 1);
        int byw = wrap80((int)fy - 1);
        int bzw = wrap80((int)fz - 1);
        int ox[4], oy[4], oz[4];
#pragma unroll
        for (int a = 0; a < 4; ++a) {
            int xa = bxw + a; if (xa >= CX) xa -= CX;
            int ya = byw + a; if (ya >= CX) ya -= CX;
            int za = bzw + a; if (za >= CX) za -= CX;
            ox[a] = xa * (CX*CX*3);
            oy[a] = ya * (CX*3);
            oz[a] = za * 3;
        }
        a0 = 0.f; a1 = 0.f; a2 = 0.f;
#pragma unroll
        for (int a = 0; a < 4; ++a) {
            float wa = wx[a];
            int oa = ox[a];
#pragma unroll
            for (int b = 0; b < 4; ++b) {
                float wab = wa * wy[b];
                int oab = oa + oy[b];
#pragma unroll
                for (int c = 0; c < 4; ++c) {
                    float w = wab * wz[c];
                    const float* p = coeff + (oab + oz[c]);
                    a0 = fmaf(w, p[0], a0);
                    a1 = fmaf(w, p[1], a1);
                    a2 = fmaf(w, p[2], a2);
                }
            }
        }
    }

    float ux = gx + a0, uy = gy + a1, uz = gz + a2;
    float o0 = M[16]*ux + M[17]*uy + M[18]*uz + M[19];
    float o1 = M[20]*ux + M[21]*uy + M[22]*uz + M[23];
    float o2 = M[24]*ux + M[25]*uy + M[26]*uz + M[27];

    out[tid*3 + 0] = o0;
    out[tid*3 + 1] = o1;
    out[tid*3 + 2] = o2;
}

// Direct path used when ws can't hold intermediates.
__global__ __launch_bounds__(256) void spline_direct(const float* __restrict__ coeff,
                                                     const float* __restrict__ M,
                                                     float* __restrict__ out) {
    int tid = blockIdx.x * 256 + threadIdx.x;
    int k = tid % FD;
    int r = tid / FD;
    int j = r % FD;
    int i = r / FD;
    float fi = (float)i, fj = (float)j, fk = (float)k;
    float gx = M[0]*fi + M[1]*fj + M[2]*fk  + M[3];
    float gy = M[4]*fi + M[5]*fj + M[6]*fk  + M[7];
    float gz = M[8]*fi + M[9]*fj + M[10]*fk + M[11];
    float fx = floorf(gx), fy = floorf(gy), fz = floorf(gz);
    float wx[4], wy[4], wz[4];
    bspline_w(gx - fx, wx);
    bspline_w(gy - fy, wy);
    bspline_w(gz - fz, wz);
    int bxw = wrap80((int)fx - 1);
    int byw = wrap80((int)fy - 1);
    int bzw = wrap80((int)fz - 1);
    int ox[4], oy[4], oz[4];
#pragma unroll
    for (int a = 0; a < 4; ++a) {
        int xa = bxw + a; if (xa >= CX) xa -= CX;
        int ya = byw + a; if (ya >= CX) ya -= CX;
        int za = bzw + a; if (za >= CX) za -= CX;
        ox[a] = xa * (CX*CX*3);
        oy[a] = ya * (CX*3);
        oz[a] = za * 3;
    }
    float a0 = 0.f, a1 = 0.f, a2 = 0.f;
#pragma unroll
    for (int a = 0; a < 4; ++a) {
        float wa = wx[a];
        int oa = ox[a];
#pragma unroll
        for (int b = 0; b < 4; ++b) {
            float wab = wa * wy[b];
            int oab = oa + oy[b];
#pragma unroll
            for (int c = 0; c < 4; ++c) {
                float w = wab * wz[c];
                const float* p = coeff + (oab + oz[c]);
                a0 = fmaf(w, p[0], a0);
                a1 = fmaf(w, p[1], a1);
                a2 = fmaf(w, p[2], a2);
            }
        }
    }
    float ux = gx + a0, uy = gy + a1, uz = gz + a2;
    float o0 = M[16]*ux + M[17]*uy + M[18]*uz + M[19];
    float o1 = M[20]*ux + M[21]*uy + M[22]*uz + M[23];
    float o2 = M[24]*ux + M[25]*uy + M[26]*uz + M[27];
    out[tid*3 + 0] = o0;
    out[tid*3 + 1] = o1;
    out[tid*3 + 2] = o2;
}

extern "C" void kernel_launch(void* const* d_in, const int* in_sizes, int n_in,
                              void* d_out, int out_size, void* d_ws, size_t ws_size,
                              hipStream_t stream) {
    const float* coeff   = (const float*)d_in[0];
    const float* affine  = (const float*)d_in[1];
    const float* fix_aff = (const float*)d_in[2];
    const float* mov_aff = (const float*)d_in[3];
    float* M   = (float*)d_ws;                                  // 64 floats
    char*  ws  = (char*)d_ws;
    float4* T1 = (float4*)(ws + 256);                           // 16,384,000 B
    float4* T2 = (float4*)(ws + 256 + (size_t)CX*CX*FD*16);     // 32,768,000 B
    float* out = (float*)d_out;

    const size_t need = 256 + (size_t)CX*CX*FD*16 + (size_t)CX*FD*FD*16;

    setup_mats<<<1, 64, 0, stream>>>(affine, fix_aff, mov_aff, M);

    const int total = FD * FD * FD;              // 4,096,000
    if (ws_size >= need) {
        pass_z<<<(CX*CX*FD)/256, 256, 0, stream>>>(coeff, M, T1);
        pass_y<<<(CX*FD*FD)/256, 256, 0, stream>>>(M, T1, T2);
        pass_x<<<total/256, 256, 0, stream>>>(coeff, M, T2, out);
    } else {
        spline_direct<<<total/256, 256, 0, stream>>>(coeff, M, out);
    }
}

// Round 4
// 43.704 us; speedup vs baseline: 3.0215x; 1.2483x over previous
//
#include <hip/hip_runtime.h>

// SplineDisp: field[v] = ma @ (g(v) + cubic_bspline_pull(coeff, g(v))),
// g(v) = fa @ v, fa = inv(affine)@fix_affine, ma = inv(mov_affine)@affine.
// Fixed size: coeff [80,80,80,3] f32, out [160,160,160,3] f32.
// R4: separable 3-pass + thread-coarsening (8 outputs/thread) along the
// filter axis in passes y and x, with a 4-deep register sliding window
// (valid because grid stride per axis is uniform and in (0,1] -> floor
// advances by 0 or 1 per output). Cuts T2 re-reads 262->~57 MB.

#define CX 80
#define FD 160

__device__ inline void inv4(const float* m, float* inv) {
    inv[0]  =  m[5]*m[10]*m[15] - m[5]*m[11]*m[14] - m[9]*m[6]*m[15] + m[9]*m[7]*m[14] + m[13]*m[6]*m[11] - m[13]*m[7]*m[10];
    inv[4]  = -m[4]*m[10]*m[15] + m[4]*m[11]*m[14] + m[8]*m[6]*m[15] - m[8]*m[7]*m[14] - m[12]*m[6]*m[11] + m[12]*m[7]*m[10];
    inv[8]  =  m[4]*m[9]*m[15]  - m[4]*m[11]*m[13] - m[8]*m[5]*m[15] + m[8]*m[7]*m[13] + m[12]*m[5]*m[11] - m[12]*m[7]*m[9];
    inv[12] = -m[4]*m[9]*m[14]  + m[4]*m[10]*m[13] + m[8]*m[5]*m[14] - m[8]*m[6]*m[13] - m[12]*m[5]*m[10] + m[12]*m[6]*m[9];
    inv[1]  = -m[1]*m[10]*m[15] + m[1]*m[11]*m[14] + m[9]*m[2]*m[15] - m[9]*m[3]*m[14] - m[13]*m[2]*m[11] + m[13]*m[3]*m[10];
    inv[5]  =  m[0]*m[10]*m[15] - m[0]*m[11]*m[14] - m[8]*m[2]*m[15] + m[8]*m[3]*m[14] + m[12]*m[2]*m[11] - m[12]*m[3]*m[10];
    inv[9]  = -m[0]*m[9]*m[15]  + m[0]*m[11]*m[13] + m[8]*m[1]*m[15] - m[8]*m[3]*m[13] - m[12]*m[1]*m[11] + m[12]*m[3]*m[9];
    inv[13] =  m[0]*m[9]*m[14]  - m[0]*m[10]*m[13] - m[8]*m[1]*m[14] + m[8]*m[2]*m[13] + m[12]*m[1]*m[10] - m[12]*m[2]*m[9];
    inv[2]  =  m[1]*m[6]*m[15]  - m[1]*m[7]*m[14]  - m[5]*m[2]*m[15] + m[5]*m[3]*m[14] + m[13]*m[2]*m[7]  - m[13]*m[3]*m[6];
    inv[6]  = -m[0]*m[6]*m[15]  + m[0]*m[7]*m[14]  + m[4]*m[2]*m[15] - m[4]*m[3]*m[14] - m[12]*m[2]*m[7]  + m[12]*m[3]*m[6];
    inv[10] =  m[0]*m[5]*m[15]  - m[0]*m[7]*m[13]  - m[4]*m[1]*m[15] + m[4]*m[3]*m[13] + m[12]*m[1]*m[7]  - m[12]*m[3]*m[5];
    inv[14] = -m[0]*m[5]*m[14]  + m[0]*m[6]*m[13]  + m[4]*m[1]*m[14] - m[4]*m[2]*m[13] - m[12]*m[1]*m[6]  + m[12]*m[2]*m[5];
    inv[3]  = -m[1]*m[6]*m[11]  + m[1]*m[7]*m[10]  + m[5]*m[2]*m[11] - m[5]*m[3]*m[10] - m[9]*m[2]*m[7]   + m[9]*m[3]*m[6];
    inv[7]  =  m[0]*m[6]*m[11]  - m[0]*m[7]*m[10]  - m[4]*m[2]*m[11] + m[4]*m[3]*m[10] + m[8]*m[2]*m[7]   - m[8]*m[3]*m[6];
    inv[11] = -m[0]*m[5]*m[11]  + m[0]*m[7]*m[9]   + m[4]*m[1]*m[11] - m[4]*m[3]*m[9]  - m[8]*m[1]*m[7]   + m[8]*m[3]*m[5];
    inv[15] =  m[0]*m[5]*m[10]  - m[0]*m[6]*m[9]   - m[4]*m[1]*m[10] + m[4]*m[2]*m[9]  + m[8]*m[1]*m[6]   - m[8]*m[2]*m[5];
    float det = m[0]*inv[0] + m[1]*inv[4] + m[2]*inv[8] + m[3]*inv[12];
    float rdet = 1.0f / det;
    for (int i = 0; i < 16; ++i) inv[i] *= rdet;
}

// M[0..15]=fa, M[16..31]=ma, M[32]=separable flag (axis-aligned AND 0<diag<=1)
__global__ void setup_mats(const float* __restrict__ affine,
                           const float* __restrict__ fix_aff,
                           const float* __restrict__ mov_aff,
                           float* __restrict__ M) {
    if (threadIdx.x != 0 || blockIdx.x != 0) return;
    float invA[16], invM[16];
    inv4(affine, invA);
    inv4(mov_aff, invM);
    for (int r = 0; r < 4; ++r)
        for (int c = 0; c < 4; ++c) {
            float s = 0.f;
            for (int k = 0; k < 4; ++k) s += invA[r*4+k] * fix_aff[k*4+c];
            M[r*4+c] = s;
        }
    for (int r = 0; r < 4; ++r)
        for (int c = 0; c < 4; ++c) {
            float s = 0.f;
            for (int k = 0; k < 4; ++k) s += invM[r*4+k] * affine[k*4+c];
            M[16 + r*4+c] = s;
        }
    float od = fabsf(M[1]) + fabsf(M[2]) + fabsf(M[4]) + fabsf(M[6]) + fabsf(M[8]) + fabsf(M[9]);
    int ok = (od < 1e-20f)
          && (M[0]  > 0.f) && (M[0]  <= 1.f)
          && (M[5]  > 0.f) && (M[5]  <= 1.f)
          && (M[10] > 0.f) && (M[10] <= 1.f);
    M[32] = ok ? 1.f : 0.f;
}

__device__ inline void bspline_w(float t, float w[4]) {
    float t2 = t * t;
    float t3 = t2 * t;
    const float s = 1.0f / 6.0f;
    w[0] = (1.f - 3.f*t + 3.f*t2 - t3) * s;
    w[1] = (4.f - 6.f*t2 + 3.f*t3) * s;
    w[2] = (1.f + 3.f*t + 3.f*t2 - 3.f*t3) * s;
    w[3] = t3 * s;
}

__device__ inline int wrap80(int v) {
    int r = v % CX;
    return (r < 0) ? r + CX : r;
}

// Pass 1: z-interp. T1[x][y][k] = sum_c wz[k][c]*coeff[x][y][zc]. 1,024,000 thr.
__global__ __launch_bounds__(256) void pass_z(const float* __restrict__ coeff,
                                              const float* __restrict__ M,
                                              float4* __restrict__ T1) {
    if (M[32] == 0.f) return;
    int tid = blockIdx.x * 256 + threadIdx.x;
    int k = tid % FD;
    int r = tid / FD;          // r = x*80 + y
    float gz = M[10] * (float)k + M[11];
    float fz = floorf(gz);
    float wz[4];
    bspline_w(gz - fz, wz);
    int bz = wrap80((int)fz - 1);
    const float* base = coeff + r * (CX * 3);
    float a0 = 0.f, a1 = 0.f, a2 = 0.f;
#pragma unroll
    for (int c = 0; c < 4; ++c) {
        int zc = bz + c; if (zc >= CX) zc -= CX;
        const float* p = base + zc * 3;
        float w = wz[c];
        a0 = fmaf(w, p[0], a0);
        a1 = fmaf(w, p[1], a1);
        a2 = fmaf(w, p[2], a2);
    }
    float4 v; v.x = a0; v.y = a1; v.z = a2; v.w = 0.f;
    T1[tid] = v;
}

// Pass 2: y-interp, coarsened 8 j's per thread with register sliding window.
// T2[x][j][k] = sum_b wy[j][b] * T1[x][yb][k]. 80*20*160 = 256,000 threads.
__global__ __launch_bounds__(256) void pass_y_c(const float* __restrict__ M,
                                                const float4* __restrict__ T1,
                                                float4* __restrict__ T2) {
    if (M[32] == 0.f) return;
    int tid = blockIdx.x * 256 + threadIdx.x;
    int k = tid % FD;
    int r = tid / FD;
    int jg = r % 20;
    int x = r / 20;
    int j0 = jg * 8;

    const float m5 = M[5], m7 = M[7];
    const float4* Tx = T1 + (size_t)x * CX * FD + k;

    float gy = m5 * (float)j0 + m7;
    float fy = floorf(gy);
    int nb = (int)fy - 1;
    float wy[4];
    bspline_w(gy - fy, wy);

    float4 w0, w1, w2, w3;
    {
        int y0 = wrap80(nb);
        int y1 = y0 + 1; if (y1 >= CX) y1 -= CX;
        int y2 = y1 + 1; if (y2 >= CX) y2 -= CX;
        int y3 = y2 + 1; if (y3 >= CX) y3 -= CX;
        w0 = Tx[(size_t)y0 * FD];
        w1 = Tx[(size_t)y1 * FD];
        w2 = Tx[(size_t)y2 * FD];
        w3 = Tx[(size_t)y3 * FD];
    }

    float4* To = T2 + ((size_t)(x * FD + j0)) * FD + k;
#pragma unroll
    for (int d = 0; d < 8; ++d) {
        if (d > 0) {
            int j = j0 + d;
            gy = m5 * (float)j + m7;
            fy = floorf(gy);
            int b2 = (int)fy - 1;
            if (b2 != nb) {                 // advance window by 1 (stride<=1)
                w0 = w1; w1 = w2; w2 = w3;
                w3 = Tx[(size_t)wrap80(b2 + 3) * FD];
                nb = b2;
            }
            bspline_w(gy - fy, wy);
        }
        float a0 = wy[0]*w0.x + wy[1]*w1.x + wy[2]*w2.x + wy[3]*w3.x;
        float a1 = wy[0]*w0.y + wy[1]*w1.y + wy[2]*w2.y + wy[3]*w3.y;
        float a2 = wy[0]*w0.z + wy[1]*w1.z + wy[2]*w2.z + wy[3]*w3.z;
        float4 v; v.x = a0; v.y = a1; v.z = a2; v.w = 0.f;
        To[(size_t)d * FD] = v;
    }
}

// Pass 3: x-interp + displacement + ma affine, coarsened 8 i's per thread.
// 20*160*160 = 512,000 threads. Window shift is wave-uniform (ig per block).
__global__ __launch_bounds__(256) void pass_x_c(const float* __restrict__ coeff,
                                                const float* __restrict__ M,
                                                const float4* __restrict__ T2,
                                                float* __restrict__ out) {
    int tid = blockIdx.x * 256 + threadIdx.x;
    int k = tid % FD;
    int r = tid / FD;
    int j = r % FD;
    int ig = r / FD;
    int i0 = ig * 8;

    if (M[32] != 0.f) {
        const float m0 = M[0], m3 = M[3];
        const float gy = M[5] * (float)j + M[7];
        const float gz = M[10] * (float)k + M[11];
        const float4* Tjk = T2 + (size_t)j * FD + k;

        float gx = m0 * (float)i0 + m3;
        float fx = floorf(gx);
        int nb = (int)fx - 1;
        float wx[4];
        bspline_w(gx - fx, wx);

        float4 w0, w1, w2, w3;
        {
            int x0 = wrap80(nb);
            int x1 = x0 + 1; if (x1 >= CX) x1 -= CX;
            int x2 = x1 + 1; if (x2 >= CX) x2 -= CX;
            int x3 = x2 + 1; if (x3 >= CX) x3 -= CX;
            w0 = Tjk[(size_t)x0 * FD * FD];
            w1 = Tjk[(size_t)x1 * FD * FD];
            w2 = Tjk[(size_t)x2 * FD * FD];
            w3 = Tjk[(size_t)x3 * FD * FD];
        }

        float* po = out + (((size_t)(i0 * FD + j)) * FD + k) * 3;
#pragma unroll
        for (int d = 0; d < 8; ++d) {
            float gxd = gx;
            if (d > 0) {
                int i = i0 + d;
                gxd = m0 * (float)i + m3;
                float fx2 = floorf(gxd);
                int b2 = (int)fx2 - 1;
                if (b2 != nb) {
                    w0 = w1; w1 = w2; w2 = w3;
                    w3 = Tjk[(size_t)wrap80(b2 + 3) * FD * FD];
                    nb = b2;
                }
                bspline_w(gxd - fx2, wx);
            }
            float a0 = wx[0]*w0.x + wx[1]*w1.x + wx[2]*w2.x + wx[3]*w3.x;
            float a1 = wx[0]*w0.y + wx[1]*w1.y + wx[2]*w2.y + wx[3]*w3.y;
            float a2 = wx[0]*w0.z + wx[1]*w1.z + wx[2]*w2.z + wx[3]*w3.z;
            float ux = gxd + a0, uy = gy + a1, uz = gz + a2;
            po[0] = M[16]*ux + M[17]*uy + M[18]*uz + M[19];
            po[1] = M[20]*ux + M[21]*uy + M[22]*uz + M[23];
            po[2] = M[24]*ux + M[25]*uy + M[26]*uz + M[27];
            po += (size_t)FD * FD * 3;   // advance i by 1
        }
    } else {
        // non-separable fallback: direct 64-tap per output
        for (int d = 0; d < 8; ++d) {
            int i = i0 + d;
            float fi = (float)i, fj = (float)j, fk = (float)k;
            float gx = M[0]*fi + M[1]*fj + M[2]*fk  + M[3];
            float gy = M[4]*fi + M[5]*fj + M[6]*fk  + M[7];
            float gz = M[8]*fi + M[9]*fj + M[10]*fk + M[11];
            float fx = floorf(gx), fy = floorf(gy), fz = floorf(gz);
            float wx[4], wy[4], wz[4];
            bspline_w(gx - fx, wx);
            bspline_w(gy - fy, wy);
            bspline_w(gz - fz, wz);
            int bxw = wrap80((int)fx - 1);
            int byw = wrap80((int)fy - 1);
            int bzw = wrap80((int)fz - 1);
            int ox[4], oy[4], oz[4];
            for (int a = 0; a < 4; ++a) {
                int xa = bxw + a; if (xa >= CX) xa -= CX;
                int ya = byw + a; if (ya >= CX) ya -= CX;
                int za = bzw + a; if (za >= CX) za -= CX;
                ox[a] = xa * (CX*CX*3);
                oy[a] = ya * (CX*3);
                oz[a] = za * 3;
            }
            float a0 = 0.f, a1 = 0.f, a2 = 0.f;
            for (int a = 0; a < 4; ++a)
                for (int b = 0; b < 4; ++b)
                    for (int c = 0; c < 4; ++c) {
                        float w = wx[a] * wy[b] * wz[c];
                        const float* p = coeff + (ox[a] + oy[b] + oz[c]);
                        a0 = fmaf(w, p[0], a0);
                        a1 = fmaf(w, p[1], a1);
                        a2 = fmaf(w, p[2], a2);
                    }
            float ux = gx + a0, uy = gy + a1, uz = gz + a2;
            size_t o = ((size_t)(i * FD + j) * FD + k) * 3;
            out[o + 0] = M[16]*ux + M[17]*uy + M[18]*uz + M[19];
            out[o + 1] = M[20]*ux + M[21]*uy + M[22]*uz + M[23];
            out[o + 2] = M[24]*ux + M[25]*uy + M[26]*uz + M[27];
        }
    }
}

// Direct path used when ws can't hold intermediates.
__global__ __launch_bounds__(256) void spline_direct(const float* __restrict__ coeff,
                                                     const float* __restrict__ M,
                                                     float* __restrict__ out) {
    int tid = blockIdx.x * 256 + threadIdx.x;
    int k = tid % FD;
    int r = tid / FD;
    int j = r % FD;
    int i = r / FD;
    float fi = (float)i, fj = (float)j, fk = (float)k;
    float gx = M[0]*fi + M[1]*fj + M[2]*fk  + M[3];
    float gy = M[4]*fi + M[5]*fj + M[6]*fk  + M[7];
    float gz = M[8]*fi + M[9]*fj + M[10]*fk + M[11];
    float fx = floorf(gx), fy = floorf(gy), fz = floorf(gz);
    float wx[4], wy[4], wz[4];
    bspline_w(gx - fx, wx);
    bspline_w(gy - fy, wy);
    bspline_w(gz - fz, wz);
    int bxw = wrap80((int)fx - 1);
    int byw = wrap80((int)fy - 1);
    int bzw = wrap80((int)fz - 1);
    int ox[4], oy[4], oz[4];
#pragma unroll
    for (int a = 0; a < 4; ++a) {
        int xa = bxw + a; if (xa >= CX) xa -= CX;
        int ya = byw + a; if (ya >= CX) ya -= CX;
        int za = bzw + a; if (za >= CX) za -= CX;
        ox[a] = xa * (CX*CX*3);
        oy[a] = ya * (CX*3);
        oz[a] = za * 3;
    }
    float a0 = 0.f, a1 = 0.f, a2 = 0.f;
#pragma unroll
    for (int a = 0; a < 4; ++a)
#pragma unroll
        for (int b = 0; b < 4; ++b)
#pragma unroll
            for (int c = 0; c < 4; ++c) {
                float w = wx[a] * wy[b] * wz[c];
                const float* p = coeff + (ox[a] + oy[b] + oz[c]);
                a0 = fmaf(w, p[0], a0);
                a1 = fmaf(w, p[1], a1);
                a2 = fmaf(w, p[2], a2);
            }
    float ux = gx + a0, uy = gy + a1, uz = gz + a2;
    float o0 = M[16]*ux + M[17]*uy + M[18]*uz + M[19];
    float o1 = M[20]*ux + M[21]*uy + M[22]*uz + M[23];
    float o2 = M[24]*ux + M[25]*uy + M[26]*uz + M[27];
    out[tid*3 + 0] = o0;
    out[tid*3 + 1] = o1;
    out[tid*3 + 2] = o2;
}

extern "C" void kernel_launch(void* const* d_in, const int* in_sizes, int n_in,
                              void* d_out, int out_size, void* d_ws, size_t ws_size,
                              hipStream_t stream) {
    const float* coeff   = (const float*)d_in[0];
    const float* affine  = (const float*)d_in[1];
    const float* fix_aff = (const float*)d_in[2];
    const float* mov_aff = (const float*)d_in[3];
    float* M   = (float*)d_ws;                                  // 64 floats
    char*  ws  = (char*)d_ws;
    float4* T1 = (float4*)(ws + 256);                           // 16,384,000 B
    float4* T2 = (float4*)(ws + 256 + (size_t)CX*CX*FD*16);     // 32,768,000 B
    float* out = (float*)d_out;

    const size_t need = 256 + (size_t)CX*CX*FD*16 + (size_t)CX*FD*FD*16;

    setup_mats<<<1, 64, 0, stream>>>(affine, fix_aff, mov_aff, M);

    if (ws_size >= need) {
        pass_z<<<(CX*CX*FD)/256, 256, 0, stream>>>(coeff, M, T1);
        pass_y_c<<<(CX*20*FD)/256, 256, 0, stream>>>(M, T1, T2);
        pass_x_c<<<(20*FD*FD)/256, 256, 0, stream>>>(coeff, M, T2, out);
    } else {
        spline_direct<<<(FD*FD*FD)/256, 256, 0, stream>>>(coeff, M, out);
    }
}